// Round 1
// baseline (1164.918 us; speedup 1.0000x reference)
//
#include <hip/hip_runtime.h>

// approxmatch EMD (Fan et al.) on MI355X.
// B=4, N=M=4096, points are 3-D, layout (B, 3, N).
// dist and e=exp(level*dist) are recomputed on the fly (never materialized):
// inputs are 192 KB total -> everything compute-bound on VALU + v_exp_f32.

#define NPTS 4096
#define BATCH 4
#define EMD_EPS 1e-9f
#define TILE 512     // points staged in LDS per tile (float4 -> 8 KB)
#define ROWS 16      // rows (or cols) handled per block
#define THREADS 256  // 16 rows x 16 lanes

// ---------------------------------------------------------------- init
__global__ void emd_init_kernel(float* __restrict__ remainL,
                                float* __restrict__ remainR,
                                float* __restrict__ cost) {
    int i = blockIdx.x * blockDim.x + threadIdx.x;
    if (i < BATCH * NPTS) {
        remainL[i] = 1.0f;   // multiL = 1 (n == m)
        remainR[i] = 1.0f;   // multiR = 1
    }
    if (i < BATCH) cost[i] = 0.0f;
}

// ---------------------------------------------------------------- pass 1
// ratioL_k = remainL_k / (EPS + sum_l e_kl * remainR_l)
__global__ __launch_bounds__(THREADS) void emd_ratioL_kernel(
        const float* __restrict__ xyz1, const float* __restrict__ xyz2,
        const float* __restrict__ remainL, const float* __restrict__ remainR,
        float* __restrict__ ratioL, float level) {
    const int b = blockIdx.y;
    const int tid = threadIdx.x;
    const int sub = tid >> 4;     // row within tile
    const int lane = tid & 15;
    const int row = blockIdx.x * ROWS + sub;

    const float* x1 = xyz1 + (size_t)b * 3 * NPTS;
    const float* x2 = xyz2 + (size_t)b * 3 * NPTS;
    const float* rR = remainR + (size_t)b * NPTS;

    const float px = x1[row], py = x1[NPTS + row], pz = x1[2 * NPTS + row];

    __shared__ float4 lds[TILE];

    float acc = 0.0f;
    for (int l0 = 0; l0 < NPTS; l0 += TILE) {
        __syncthreads();
        for (int i = tid; i < TILE; i += THREADS) {
            int l = l0 + i;
            lds[i] = make_float4(x2[l], x2[NPTS + l], x2[2 * NPTS + l], rR[l]);
        }
        __syncthreads();
#pragma unroll 8
        for (int j = 0; j < TILE / 16; ++j) {
            float4 q = lds[lane + 16 * j];
            float dx = px - q.x, dy = py - q.y, dz = pz - q.z;
            float d = dx * dx + dy * dy + dz * dz;
            acc += __expf(level * d) * q.w;
        }
    }
    acc += __shfl_down(acc, 8);
    acc += __shfl_down(acc, 4);
    acc += __shfl_down(acc, 2);
    acc += __shfl_down(acc, 1);
    if (lane == 0) {
        size_t idx = (size_t)b * NPTS + row;
        ratioL[idx] = remainL[idx] / (EMD_EPS + acc);
    }
}

// ---------------------------------------------------------------- pass 2
// s_l = sum_k e_kl * ratioL_k ; sumr = remainR_l * s ;
// ratioR_l = min(remainR/(sumr+EPS),1) * remainR ; remainR = max(0, remainR - sumr)
__global__ __launch_bounds__(THREADS) void emd_ratioR_kernel(
        const float* __restrict__ xyz1, const float* __restrict__ xyz2,
        const float* __restrict__ ratioL, float* __restrict__ ratioR,
        float* __restrict__ remainR, float level) {
    const int b = blockIdx.y;
    const int tid = threadIdx.x;
    const int sub = tid >> 4;     // col within tile
    const int lane = tid & 15;
    const int col = blockIdx.x * ROWS + sub;

    const float* x1 = xyz1 + (size_t)b * 3 * NPTS;
    const float* x2 = xyz2 + (size_t)b * 3 * NPTS;
    const float* rL = ratioL + (size_t)b * NPTS;

    const float px = x2[col], py = x2[NPTS + col], pz = x2[2 * NPTS + col];

    __shared__ float4 lds[TILE];

    float acc = 0.0f;
    for (int k0 = 0; k0 < NPTS; k0 += TILE) {
        __syncthreads();
        for (int i = tid; i < TILE; i += THREADS) {
            int k = k0 + i;
            lds[i] = make_float4(x1[k], x1[NPTS + k], x1[2 * NPTS + k], rL[k]);
        }
        __syncthreads();
#pragma unroll 8
        for (int j = 0; j < TILE / 16; ++j) {
            float4 q = lds[lane + 16 * j];
            float dx = px - q.x, dy = py - q.y, dz = pz - q.z;
            float d = dx * dx + dy * dy + dz * dz;
            acc += __expf(level * d) * q.w;
        }
    }
    acc += __shfl_down(acc, 8);
    acc += __shfl_down(acc, 4);
    acc += __shfl_down(acc, 2);
    acc += __shfl_down(acc, 1);
    if (lane == 0) {
        size_t idx = (size_t)b * NPTS + col;
        float r = remainR[idx];
        float sumr = r * acc;
        float cons = fminf(r / (sumr + EMD_EPS), 1.0f);
        ratioR[idx] = cons * r;
        remainR[idx] = fmaxf(0.0f, r - sumr);
    }
}

// ---------------------------------------------------------------- pass 3
// a_k = sum_l e*ratioR_l ; c_k = sum_l e*ratioR_l*sqrt(d) ;
// remainL_k = max(0, remainL_k - ratioL_k*a_k) ; cost[b] += ratioL_k*c_k
__global__ __launch_bounds__(THREADS) void emd_cost_kernel(
        const float* __restrict__ xyz1, const float* __restrict__ xyz2,
        const float* __restrict__ ratioL, const float* __restrict__ ratioR,
        float* __restrict__ remainL, float* __restrict__ cost, float level) {
    const int b = blockIdx.y;
    const int tid = threadIdx.x;
    const int sub = tid >> 4;
    const int lane = tid & 15;
    const int row = blockIdx.x * ROWS + sub;

    const float* x1 = xyz1 + (size_t)b * 3 * NPTS;
    const float* x2 = xyz2 + (size_t)b * 3 * NPTS;
    const float* rRr = ratioR + (size_t)b * NPTS;

    const float px = x1[row], py = x1[NPTS + row], pz = x1[2 * NPTS + row];

    __shared__ float4 lds[TILE];
    __shared__ float s_cost[ROWS];

    float acc_a = 0.0f;
    float acc_c = 0.0f;
    for (int l0 = 0; l0 < NPTS; l0 += TILE) {
        __syncthreads();
        for (int i = tid; i < TILE; i += THREADS) {
            int l = l0 + i;
            lds[i] = make_float4(x2[l], x2[NPTS + l], x2[2 * NPTS + l], rRr[l]);
        }
        __syncthreads();
#pragma unroll 8
        for (int j = 0; j < TILE / 16; ++j) {
            float4 q = lds[lane + 16 * j];
            float dx = px - q.x, dy = py - q.y, dz = pz - q.z;
            float d = dx * dx + dy * dy + dz * dz;
            float er = __expf(level * d) * q.w;
            acc_a += er;
            acc_c += er * sqrtf(fmaxf(d, 1e-20f));
        }
    }
    acc_a += __shfl_down(acc_a, 8);
    acc_a += __shfl_down(acc_a, 4);
    acc_a += __shfl_down(acc_a, 2);
    acc_a += __shfl_down(acc_a, 1);
    acc_c += __shfl_down(acc_c, 8);
    acc_c += __shfl_down(acc_c, 4);
    acc_c += __shfl_down(acc_c, 2);
    acc_c += __shfl_down(acc_c, 1);
    if (lane == 0) {
        size_t idx = (size_t)b * NPTS + row;
        float rl = ratioL[idx];
        remainL[idx] = fmaxf(0.0f, remainL[idx] - rl * acc_a);
        s_cost[sub] = rl * acc_c;
    }
    __syncthreads();
    if (tid == 0) {
        float t = 0.0f;
#pragma unroll
        for (int i = 0; i < ROWS; ++i) t += s_cost[i];
        atomicAdd(&cost[b], t);
    }
}

// ---------------------------------------------------------------- finalize
__global__ void emd_final_kernel(const float* __restrict__ cost,
                                 float* __restrict__ out) {
    if (threadIdx.x == 0) {
        float s = 0.0f;
        for (int b = 0; b < BATCH; ++b) s += cost[b];
        out[0] = s / ((float)NPTS * (float)BATCH);
    }
}

extern "C" void kernel_launch(void* const* d_in, const int* in_sizes, int n_in,
                              void* d_out, int out_size, void* d_ws, size_t ws_size,
                              hipStream_t stream) {
    const float* xyz1 = (const float*)d_in[0];
    const float* xyz2 = (const float*)d_in[1];
    float* out = (float*)d_out;

    float* ws = (float*)d_ws;
    float* remainL = ws;                      // B*N
    float* remainR = ws + 1 * BATCH * NPTS;   // B*N
    float* ratioL  = ws + 2 * BATCH * NPTS;   // B*N
    float* ratioR  = ws + 3 * BATCH * NPTS;   // B*N
    float* cost    = ws + 4 * BATCH * NPTS;   // B

    emd_init_kernel<<<(BATCH * NPTS + 255) / 256, 256, 0, stream>>>(remainL, remainR, cost);

    // levels: -(4^j) for j = 7..-1, then 0  (10 sweeps)
    static const float levels[10] = {
        -16384.0f, -4096.0f, -1024.0f, -256.0f, -64.0f,
        -16.0f, -4.0f, -1.0f, -0.25f, 0.0f};

    dim3 grid(NPTS / ROWS, BATCH);
    for (int t = 0; t < 10; ++t) {
        float lv = levels[t];
        emd_ratioL_kernel<<<grid, THREADS, 0, stream>>>(xyz1, xyz2, remainL, remainR, ratioL, lv);
        emd_ratioR_kernel<<<grid, THREADS, 0, stream>>>(xyz1, xyz2, ratioL, ratioR, remainR, lv);
        emd_cost_kernel<<<grid, THREADS, 0, stream>>>(xyz1, xyz2, ratioL, ratioR, remainL, cost, lv);
    }
    emd_final_kernel<<<1, 64, 0, stream>>>(cost, out);
}

// Round 2
// 634.402 us; speedup vs baseline: 1.8362x; 1.8362x over previous
//
#include <hip/hip_runtime.h>

// approxmatch EMD (Fan et al.) on MI355X, B=4, N=M=4096, layout (B,3,N).
// Geometry: each wave owns RPW=4 rows (coords in registers), all 64 lanes
// sweep columns staged in LDS (float4/pair-eval amortized over 4 rows ->
// 4 B/pair LDS traffic). Butterfly __shfl_xor reduction at the end.
// exp(level*d) computed as v_exp_f32(ls2*d) with ls2 = level*log2(e).
// pass3(t) fused with pass1(t+1); level-0 sweep specialcased (e == 1).

#define NPTS 4096
#define BATCH 4
#define EMD_EPS 1e-9f
#define TILE 1024        // columns staged per LDS stage (16 KB as float4)
#define RPW 4            // rows (or cols) per wave, in registers
#define THREADS 256      // 4 waves
#define RPB 16           // rows per block = 4 waves * RPW
#define NBLK (NPTS / RPB)  // 256 row-blocks per batch
#define LOG2E 1.4426950408889634f

__device__ __forceinline__ float fexp2(float x) {
#if __has_builtin(__builtin_amdgcn_exp2f)
    return __builtin_amdgcn_exp2f(x);
#else
    return exp2f(x);
#endif
}
__device__ __forceinline__ float fsqrt(float x) {
#if __has_builtin(__builtin_amdgcn_sqrtf)
    return __builtin_amdgcn_sqrtf(x);
#else
    return __sqrtf(x);
#endif
}

__device__ __forceinline__ float wave_reduce(float v) {
    v += __shfl_xor(v, 32);
    v += __shfl_xor(v, 16);
    v += __shfl_xor(v, 8);
    v += __shfl_xor(v, 4);
    v += __shfl_xor(v, 2);
    v += __shfl_xor(v, 1);
    return v;
}

// ---------------------------------------------------------------- init
__global__ void k_init(float* __restrict__ remainL, float* __restrict__ remainR,
                       float* __restrict__ cost_part) {
    int i = blockIdx.x * blockDim.x + threadIdx.x;
    if (i < BATCH * NPTS) {
        remainL[i] = 1.0f;   // multiL = 1 (n == m)
        remainR[i] = 1.0f;
    }
    if (i < BATCH * NBLK) cost_part[i] = 0.0f;
}

// ---------------------------------------------------------------- pass 1 (sweep 0 only)
// ratioL_k = remainL_k / (EPS + sum_l exp2(ls2*d) * remainR_l)
__global__ __launch_bounds__(THREADS, 4) void k_ratioL(
        const float* __restrict__ xyz1, const float* __restrict__ xyz2,
        const float* __restrict__ remainL, const float* __restrict__ remainR,
        float* __restrict__ ratioL, float ls2) {
    const int b = blockIdx.y;
    const int tid = threadIdx.x;
    const int wave = tid >> 6;
    const int lane = tid & 63;
    const int row0 = blockIdx.x * RPB + wave * RPW;

    const float* x1 = xyz1 + b * 3 * NPTS;
    const float* x2 = xyz2 + b * 3 * NPTS;
    const float* rR = remainR + b * NPTS;

    float px[RPW], py[RPW], pz[RPW], acc[RPW];
#pragma unroll
    for (int r = 0; r < RPW; ++r) {
        px[r] = x1[row0 + r];
        py[r] = x1[NPTS + row0 + r];
        pz[r] = x1[2 * NPTS + row0 + r];
        acc[r] = 0.0f;
    }
    __shared__ float4 lds[TILE];

    for (int c0 = 0; c0 < NPTS; c0 += TILE) {
        __syncthreads();
        for (int i = tid; i < TILE; i += THREADS) {
            int l = c0 + i;
            lds[i] = make_float4(x2[l], x2[NPTS + l], x2[2 * NPTS + l], rR[l]);
        }
        __syncthreads();
#pragma unroll 4
        for (int j = 0; j < TILE / 64; ++j) {
            float4 q = lds[lane + 64 * j];
#pragma unroll
            for (int r = 0; r < RPW; ++r) {
                float dx = px[r] - q.x, dy = py[r] - q.y, dz = pz[r] - q.z;
                float d = fmaf(dx, dx, fmaf(dy, dy, dz * dz));
                acc[r] = fmaf(fexp2(ls2 * d), q.w, acc[r]);
            }
        }
    }
#pragma unroll
    for (int r = 0; r < RPW; ++r) acc[r] = wave_reduce(acc[r]);
    if (lane == 0) {
#pragma unroll
        for (int r = 0; r < RPW; ++r) {
            int idx = b * NPTS + row0 + r;
            ratioL[idx] = remainL[idx] / (EMD_EPS + acc[r]);
        }
    }
}

// ---------------------------------------------------------------- pass 2
// per column l: s = sum_k e*ratioL_k ; sumr = remainR*s ;
// ratioR = min(remainR/(sumr+EPS),1)*remainR ; remainR = max(0, remainR-sumr)
__global__ __launch_bounds__(THREADS, 4) void k_ratioR(
        const float* __restrict__ xyz1, const float* __restrict__ xyz2,
        const float* __restrict__ ratioL, float* __restrict__ ratioR,
        float* __restrict__ remainR, float ls2) {
    const int b = blockIdx.y;
    const int tid = threadIdx.x;
    const int wave = tid >> 6;
    const int lane = tid & 63;
    const int col0 = blockIdx.x * RPB + wave * RPW;

    const float* x1 = xyz1 + b * 3 * NPTS;
    const float* x2 = xyz2 + b * 3 * NPTS;
    const float* rL = ratioL + b * NPTS;

    float px[RPW], py[RPW], pz[RPW], acc[RPW];
#pragma unroll
    for (int r = 0; r < RPW; ++r) {
        px[r] = x2[col0 + r];
        py[r] = x2[NPTS + col0 + r];
        pz[r] = x2[2 * NPTS + col0 + r];
        acc[r] = 0.0f;
    }
    __shared__ float4 lds[TILE];

    for (int k0 = 0; k0 < NPTS; k0 += TILE) {
        __syncthreads();
        for (int i = tid; i < TILE; i += THREADS) {
            int k = k0 + i;
            lds[i] = make_float4(x1[k], x1[NPTS + k], x1[2 * NPTS + k], rL[k]);
        }
        __syncthreads();
#pragma unroll 4
        for (int j = 0; j < TILE / 64; ++j) {
            float4 q = lds[lane + 64 * j];
#pragma unroll
            for (int r = 0; r < RPW; ++r) {
                float dx = px[r] - q.x, dy = py[r] - q.y, dz = pz[r] - q.z;
                float d = fmaf(dx, dx, fmaf(dy, dy, dz * dz));
                acc[r] = fmaf(fexp2(ls2 * d), q.w, acc[r]);
            }
        }
    }
#pragma unroll
    for (int r = 0; r < RPW; ++r) acc[r] = wave_reduce(acc[r]);
    if (lane == 0) {
#pragma unroll
        for (int r = 0; r < RPW; ++r) {
            int idx = b * NPTS + col0 + r;
            float rv = remainR[idx];
            float sumr = rv * acc[r];
            float cons = fminf(rv / (sumr + EMD_EPS), 1.0f);
            ratioR[idx] = cons * rv;
            remainR[idx] = fmaxf(0.0f, rv - sumr);
        }
    }
}

// ---------------------------------------------------------------- pass 3(t) + pass 1(t+1) fused
// acc_a = sum_l e_t*ratioR_l        -> remainL update
// acc_c = sum_l e_t*ratioR_l*sqrt(d) -> cost contribution
// acc_s = sum_l e_{t+1}*remainR_l    -> next sweep's suml -> new ratioL
// (ls2n == 0 for t=8 gives e_{t+1} == 1, exactly the level-0 suml)
__global__ __launch_bounds__(THREADS, 4) void k_cost_fused(
        const float* __restrict__ xyz1, const float* __restrict__ xyz2,
        float* __restrict__ ratioL, const float* __restrict__ ratioR,
        float* __restrict__ remainL, const float* __restrict__ remainR,
        float* __restrict__ cost_part, float ls2, float ls2n) {
    const int b = blockIdx.y;
    const int tid = threadIdx.x;
    const int wave = tid >> 6;
    const int lane = tid & 63;
    const int row0 = blockIdx.x * RPB + wave * RPW;

    const float* x1 = xyz1 + b * 3 * NPTS;
    const float* x2 = xyz2 + b * 3 * NPTS;
    const float* rRr = ratioR + b * NPTS;
    const float* rmR = remainR + b * NPTS;

    float px[RPW], py[RPW], pz[RPW], acc_a[RPW], acc_c[RPW], acc_s[RPW];
#pragma unroll
    for (int r = 0; r < RPW; ++r) {
        px[r] = x1[row0 + r];
        py[r] = x1[NPTS + row0 + r];
        pz[r] = x1[2 * NPTS + row0 + r];
        acc_a[r] = 0.0f; acc_c[r] = 0.0f; acc_s[r] = 0.0f;
    }
    __shared__ float4 lds[TILE];
    __shared__ float ldsw[TILE];
    __shared__ float s_cost[THREADS / 64];

    for (int c0 = 0; c0 < NPTS; c0 += TILE) {
        __syncthreads();
        for (int i = tid; i < TILE; i += THREADS) {
            int l = c0 + i;
            lds[i] = make_float4(x2[l], x2[NPTS + l], x2[2 * NPTS + l], rRr[l]);
            ldsw[i] = rmR[l];
        }
        __syncthreads();
#pragma unroll 4
        for (int j = 0; j < TILE / 64; ++j) {
            float4 q = lds[lane + 64 * j];
            float w2 = ldsw[lane + 64 * j];
#pragma unroll
            for (int r = 0; r < RPW; ++r) {
                float dx = px[r] - q.x, dy = py[r] - q.y, dz = pz[r] - q.z;
                float d = fmaf(dx, dx, fmaf(dy, dy, dz * dz));
                float er = fexp2(ls2 * d) * q.w;
                acc_a[r] += er;
                acc_c[r] = fmaf(er, fsqrt(d), acc_c[r]);
                acc_s[r] = fmaf(fexp2(ls2n * d), w2, acc_s[r]);
            }
        }
    }
#pragma unroll
    for (int r = 0; r < RPW; ++r) {
        acc_a[r] = wave_reduce(acc_a[r]);
        acc_c[r] = wave_reduce(acc_c[r]);
        acc_s[r] = wave_reduce(acc_s[r]);
    }
    if (lane == 0) {
        float wcost = 0.0f;
#pragma unroll
        for (int r = 0; r < RPW; ++r) {
            int idx = b * NPTS + row0 + r;
            float rl = ratioL[idx];
            float rem = fmaxf(0.0f, remainL[idx] - rl * acc_a[r]);
            remainL[idx] = rem;
            ratioL[idx] = rem / (EMD_EPS + acc_s[r]);   // next sweep's ratioL
            wcost = fmaf(rl, acc_c[r], wcost);
        }
        s_cost[wave] = wcost;
    }
    __syncthreads();
    if (tid == 0) {
        float t = s_cost[0] + s_cost[1] + s_cost[2] + s_cost[3];
        cost_part[b * NBLK + blockIdx.x] += t;   // exclusive owner, accumulates over sweeps
    }
}

// ---------------------------------------------------------------- level-0 small kernels
// S_L[b] = sum_k ratioL_k  (one block per batch; deterministic)
__global__ void k_sum_ratioL(const float* __restrict__ ratioL, float* __restrict__ S_L) {
    const int b = blockIdx.x;
    const int tid = threadIdx.x;
    float s = 0.0f;
    for (int i = tid; i < NPTS; i += 256) s += ratioL[b * NPTS + i];
    s = wave_reduce(s);
    __shared__ float sw[4];
    if ((tid & 63) == 0) sw[tid >> 6] = s;
    __syncthreads();
    if (tid == 0) S_L[b] = sw[0] + sw[1] + sw[2] + sw[3];
}

// level 0: e == 1 -> sumr_l = remainR_l * S_L[b]; ratioR elementwise
__global__ void k_ratioR_l0(const float* __restrict__ remainR,
                            const float* __restrict__ S_L,
                            float* __restrict__ ratioR) {
    int i = blockIdx.x * blockDim.x + threadIdx.x;
    int b = i >> 12;                       // NPTS = 4096
    float rv = remainR[i];
    float sumr = rv * S_L[b];
    float cons = fminf(rv / (sumr + EMD_EPS), 1.0f);
    ratioR[i] = cons * rv;                 // remainR never read again
}

// level 0 cost pass: e == 1 -> c_k = sum_l ratioR_l*sqrt(d); cost += ratioL_k*c_k
__global__ __launch_bounds__(THREADS, 4) void k_cost_l0(
        const float* __restrict__ xyz1, const float* __restrict__ xyz2,
        const float* __restrict__ ratioL, const float* __restrict__ ratioR,
        float* __restrict__ cost_part) {
    const int b = blockIdx.y;
    const int tid = threadIdx.x;
    const int wave = tid >> 6;
    const int lane = tid & 63;
    const int row0 = blockIdx.x * RPB + wave * RPW;

    const float* x1 = xyz1 + b * 3 * NPTS;
    const float* x2 = xyz2 + b * 3 * NPTS;
    const float* rRr = ratioR + b * NPTS;

    float px[RPW], py[RPW], pz[RPW], acc_c[RPW];
#pragma unroll
    for (int r = 0; r < RPW; ++r) {
        px[r] = x1[row0 + r];
        py[r] = x1[NPTS + row0 + r];
        pz[r] = x1[2 * NPTS + row0 + r];
        acc_c[r] = 0.0f;
    }
    __shared__ float4 lds[TILE];
    __shared__ float s_cost[THREADS / 64];

    for (int c0 = 0; c0 < NPTS; c0 += TILE) {
        __syncthreads();
        for (int i = tid; i < TILE; i += THREADS) {
            int l = c0 + i;
            lds[i] = make_float4(x2[l], x2[NPTS + l], x2[2 * NPTS + l], rRr[l]);
        }
        __syncthreads();
#pragma unroll 4
        for (int j = 0; j < TILE / 64; ++j) {
            float4 q = lds[lane + 64 * j];
#pragma unroll
            for (int r = 0; r < RPW; ++r) {
                float dx = px[r] - q.x, dy = py[r] - q.y, dz = pz[r] - q.z;
                float d = fmaf(dx, dx, fmaf(dy, dy, dz * dz));
                acc_c[r] = fmaf(q.w, fsqrt(d), acc_c[r]);
            }
        }
    }
#pragma unroll
    for (int r = 0; r < RPW; ++r) acc_c[r] = wave_reduce(acc_c[r]);
    if (lane == 0) {
        float wcost = 0.0f;
#pragma unroll
        for (int r = 0; r < RPW; ++r) {
            int idx = b * NPTS + row0 + r;
            wcost = fmaf(ratioL[idx], acc_c[r], wcost);
        }
        s_cost[wave] = wcost;
    }
    __syncthreads();
    if (tid == 0) {
        float t = s_cost[0] + s_cost[1] + s_cost[2] + s_cost[3];
        cost_part[b * NBLK + blockIdx.x] += t;
    }
}

// ---------------------------------------------------------------- finalize
__global__ void k_final(const float* __restrict__ cost_part, float* __restrict__ out) {
    const int tid = threadIdx.x;
    float s = 0.0f;
    for (int i = tid; i < BATCH * NBLK; i += 256) s += cost_part[i];
    s = wave_reduce(s);
    __shared__ float sw[4];
    if ((tid & 63) == 0) sw[tid >> 6] = s;
    __syncthreads();
    if (tid == 0) out[0] = (sw[0] + sw[1] + sw[2] + sw[3]) / ((float)NPTS * (float)BATCH);
}

extern "C" void kernel_launch(void* const* d_in, const int* in_sizes, int n_in,
                              void* d_out, int out_size, void* d_ws, size_t ws_size,
                              hipStream_t stream) {
    const float* xyz1 = (const float*)d_in[0];
    const float* xyz2 = (const float*)d_in[1];
    float* out = (float*)d_out;

    float* ws = (float*)d_ws;
    float* remainL  = ws;                      // B*N
    float* remainR  = ws + 1 * BATCH * NPTS;   // B*N
    float* ratioL   = ws + 2 * BATCH * NPTS;   // B*N
    float* ratioR   = ws + 3 * BATCH * NPTS;   // B*N
    float* cost_part = ws + 4 * BATCH * NPTS;  // B*NBLK
    float* S_L      = cost_part + BATCH * NBLK; // B

    // levels: -(4^j) for j = 7..-1, then 0; premultiplied by log2(e)
    static const float levels[10] = {
        -16384.0f, -4096.0f, -1024.0f, -256.0f, -64.0f,
        -16.0f, -4.0f, -1.0f, -0.25f, 0.0f};
    float ls2[10];
    for (int t = 0; t < 10; ++t) ls2[t] = levels[t] * LOG2E;

    dim3 grid(NBLK, BATCH);

    k_init<<<(BATCH * NPTS + 255) / 256, 256, 0, stream>>>(remainL, remainR, cost_part);
    k_ratioL<<<grid, THREADS, 0, stream>>>(xyz1, xyz2, remainL, remainR, ratioL, ls2[0]);
    for (int t = 0; t < 9; ++t) {
        k_ratioR<<<grid, THREADS, 0, stream>>>(xyz1, xyz2, ratioL, ratioR, remainR, ls2[t]);
        k_cost_fused<<<grid, THREADS, 0, stream>>>(xyz1, xyz2, ratioL, ratioR,
                                                   remainL, remainR, cost_part,
                                                   ls2[t], ls2[t + 1]);
    }
    // sweep 9 (level == 0): pass1/pass2 collapse to vector ops
    k_sum_ratioL<<<BATCH, 256, 0, stream>>>(ratioL, S_L);
    k_ratioR_l0<<<(BATCH * NPTS) / 256, 256, 0, stream>>>(remainR, S_L, ratioR);
    k_cost_l0<<<grid, THREADS, 0, stream>>>(xyz1, xyz2, ratioL, ratioR, cost_part);
    k_final<<<1, 256, 0, stream>>>(cost_part, out);
}